// Round 10
// baseline (105.311 us; speedup 1.0000x reference)
//
#include <hip/hip_runtime.h>

static constexpr float EPSF = 1e-6f;

// Coefficient table, float4 k-pair packed, lane-coherent:
//   C4[(set*3+ch)*512 + kk*32 + ln] = { p[2kk], sn[2kk], p[2kk+1], sn[2kk+1] }
// p_k = 1/denom_k, sn_k = -c*_k for solve-line ln.
// Sets 0..5  : x-direction, t = 0.1*set,          dt = DT/2 = 0.05
// Sets 6..10 : y-direction, t = 0.1*(set-6)+0.05, dt = DT   = 0.10

__global__ __launch_bounds__(64) void coef_kernel(
    const float* __restrict__ alpha_base, const float* __restrict__ beta_base,
    const float* __restrict__ alpha_tc,   const float* __restrict__ beta_tc,
    float4* __restrict__ C4)
{
    int gid  = blockIdx.x * 64 + threadIdx.x;
    int pair = gid >> 5;          // (set,ch) index, 0..32
    int ln   = gid & 31;
    if (pair >= 33) return;
    int set = pair / 3;
    int ch  = pair % 3;
    bool isX = (set < 6);
    float t  = isX ? 0.1f * (float)set : 0.1f * (float)(set - 6) + 0.05f;
    float dt = isX ? 0.05f : 0.1f;

    const float* bp; const float* tp; int stride;
    if (isX) { bp = alpha_base + (ch * 32 + ln) * 32; tp = alpha_tc + (ch * 32 + ln) * 32; stride = 1; }
    else     { bp = beta_base  + ch * 1024 + ln;      tp = beta_tc  + ch * 1024 + ln;      stride = 32; }

    float c[32];
    #pragma unroll
    for (int i = 0; i < 32; ++i)
        c[i] = fmaxf(fmaf(tp[i * stride], t, bp[i * stride]), EPSF);

    // replicate-pad 3-tap mean, scaled by dt (dh = 1)
    float cs[32];
    #pragma unroll
    for (int i = 0; i < 32; ++i) {
        float l = (i == 0)  ? c[0]  : c[i - 1];
        float r = (i == 31) ? c[31] : c[i + 1];
        cs[i] = (l + c[i] + r) / 3.0f * dt;
    }

    // Thomas coefficient recurrence: b_i = 1+2cs_i (ends 1+cs), a_i = c_i = -cs_i, a_0 := 0
    float p[32], sn[32];
    {
        float den = (1.0f + cs[0]) + EPSF;
        p[0]  = 1.0f / den;
        sn[0] = cs[0] * p[0];
        float sprev = -sn[0];
        #pragma unroll
        for (int i = 1; i < 32; ++i) {
            float bi = (i == 31) ? (1.0f + cs[31]) : fmaf(2.0f, cs[i], 1.0f);
            float ai = -cs[i];
            float dd = (bi - ai * sprev) + EPSF;
            float pi = 1.0f / dd;
            p[i]  = pi;
            float si = ai * pi;
            sn[i] = -si;
            sprev = si;
        }
    }

    float4* o = C4 + (set * 3 + ch) * 512 + ln;
    #pragma unroll
    for (int kk = 0; kk < 16; ++kk)
        o[kk * 32] = make_float4(p[2 * kk], sn[2 * kk], p[2 * kk + 1], sn[2 * kk + 1]);
}

// Batch-load one coefficient set: 16 lane-coherent dwordx4 (no deps).
__device__ __forceinline__ void loadc4(float p[32], float sn[32],
                                       const float4* __restrict__ c)
{
    #pragma unroll
    for (int kk = 0; kk < 16; ++kk) {
        float4 v = c[kk * 32];
        p[2 * kk]      = v.x; sn[2 * kk]     = v.y;
        p[2 * kk + 1]  = v.z; sn[2 * kk + 1] = v.w;
    }
}

// Quad-slab register Thomas solve: d[i] = {A,B,C,D}, shared coefficients.
// Four interleaved chains -> dep latency fully covered by issue.
__device__ __forceinline__ void solve4(float4 d[32], const float p[32], const float sn[32])
{
    float4 prev;
    prev.x = d[0].x * p[0];
    prev.y = d[0].y * p[0];
    prev.z = d[0].z * p[0];
    prev.w = d[0].w * p[0];
    d[0] = prev;
    #pragma unroll
    for (int i = 1; i < 32; ++i) {
        prev.x = fmaf(sn[i], prev.x, d[i].x * p[i]);
        prev.y = fmaf(sn[i], prev.y, d[i].y * p[i]);
        prev.z = fmaf(sn[i], prev.z, d[i].z * p[i]);
        prev.w = fmaf(sn[i], prev.w, d[i].w * p[i]);
        d[i] = prev;
    }
    #pragma unroll
    for (int i = 30; i >= 0; --i) {
        d[i].x = fmaf(sn[i], d[i + 1].x, d[i].x);
        d[i].y = fmaf(sn[i], d[i + 1].y, d[i].y);
        d[i].z = fmaf(sn[i], d[i + 1].z, d[i].z);
        d[i].w = fmaf(sn[i], d[i + 1].w, d[i].w);
    }
}

// ---------------------------------------------------------------------------
// Main kernel: ONE WAVE per block, 2 half-waves x 1 slab-QUAD each (8 slabs).
// LDS cell = float4{A,B,C,D}. Row = 32 cells, row stride 33 float4 ->
// rows AND cols are b128: 16 DS wave-ops per slab-step (vs 24 in pair
// version). solve4 = 4-way ILP chains. Zero barriers (all wave-local).
// __launch_bounds__(64,1): no VGPR cap -> no spill (round-5 lesson).
// ---------------------------------------------------------------------------
__global__ __launch_bounds__(64, 1) void diff_kernel(
    const float* __restrict__ u_in, float* __restrict__ u_out,
    const float4* __restrict__ C4, int blocksPerCh)
{
    __shared__ float4 tile4[2 * 1058];  // 2 quads x (32 rows x 33 f4 + 2 pad)
    const int l   = threadIdx.x;        // 0..63
    const int bid = blockIdx.x;
    const int ch  = bid / blocksPerCh;
    const int b0  = (bid % blocksPerCh) * 8;
    const int h   = l >> 5;             // quad index 0..1
    const int ln  = l & 31;             // line index

    const int bA = b0 + h * 4;          // this half-wave's batches bA..bA+3
    const float4* gA = reinterpret_cast<const float4*>(u_in + (bA * 3 + ch) * 1024);
    const float4* gB = gA + 768;        // +1 batch, same ch (3072 floats)
    const float4* gC = gA + 1536;
    const float4* gD = gA + 2304;
    float4* T4 = tile4 + h * 1058;

    const float4* cb = C4 + ch * 512 + ln;   // + set*1536
    float p[32], sn[32];
    loadc4(p, sn, cb);                  // x set 0 in flight
    __builtin_amdgcn_sched_barrier(0);

    // ---- stage 4 slabs, interleaved into float4 cells (all b128) ----
    const int srow = ln >> 3, schk = ln & 7;
    #pragma unroll
    for (int r = 0; r < 8; ++r) {
        const int row = r * 4 + srow;
        float4 a = gA[row * 8 + schk];
        float4 b = gB[row * 8 + schk];
        float4 c = gC[row * 8 + schk];
        float4 e = gD[row * 8 + schk];
        float4* dst = T4 + row * 33 + 4 * schk;
        dst[0] = make_float4(a.x, b.x, c.x, e.x);
        dst[1] = make_float4(a.y, b.y, c.y, e.y);
        dst[2] = make_float4(a.z, b.z, c.z, e.z);
        dst[3] = make_float4(a.w, b.w, c.w, e.w);
    }

    float4 d[32];
    #pragma unroll
    for (int j = 0; j < 32; ++j)        // read row ln (b128)
        d[j] = T4[ln * 33 + j];
    solve4(d, p, sn);                   // X, set 0

    const float4* cy = cb + 6 * 1536;   // y sets 6..10
    const float4* cx = cb + 1 * 1536;   // x sets 1..5

    for (int step = 0; step < 5; ++step) {
        // ---- y full-step ----
        loadc4(p, sn, cy); cy += 1536;
        __builtin_amdgcn_sched_barrier(0);
        #pragma unroll
        for (int j = 0; j < 32; ++j)    // write rows (b128)
            T4[ln * 33 + j] = d[j];
        #pragma unroll
        for (int i = 0; i < 32; ++i)    // read cols (b128)
            d[i] = T4[i * 33 + ln];
        solve4(d, p, sn);               // Y, set 6+step

        // ---- x half-step pair (set step+1, shared coefs) ----
        loadc4(p, sn, cx); cx += 1536;
        __builtin_amdgcn_sched_barrier(0);
        #pragma unroll
        for (int i = 0; i < 32; ++i)    // write cols (b128)
            T4[i * 33 + ln] = d[i];
        #pragma unroll
        for (int j = 0; j < 32; ++j)    // read rows (b128)
            d[j] = T4[ln * 33 + j];
        solve4(d, p, sn);               // xb(step) == xa(step+1): same set
        if (step < 4) solve4(d, p, sn);
    }

    // ---- writeback: rows -> LDS (b128), de-interleave, coalesced out ----
    #pragma unroll
    for (int j = 0; j < 32; ++j)
        T4[ln * 33 + j] = d[j];
    float4* oA = reinterpret_cast<float4*>(u_out + (bA * 3 + ch) * 1024);
    float4* oB = oA + 768;
    float4* oC = oA + 1536;
    float4* oD = oA + 2304;
    #pragma unroll
    for (int r = 0; r < 8; ++r) {
        const int row = r * 4 + srow;
        const float4* src = T4 + row * 33 + 4 * schk;
        float4 c0 = src[0], c1 = src[1], c2 = src[2], c3 = src[3];
        oA[row * 8 + schk] = make_float4(c0.x, c1.x, c2.x, c3.x);
        oB[row * 8 + schk] = make_float4(c0.y, c1.y, c2.y, c3.y);
        oC[row * 8 + schk] = make_float4(c0.z, c1.z, c2.z, c3.z);
        oD[row * 8 + schk] = make_float4(c0.w, c1.w, c2.w, c3.w);
    }
}

extern "C" void kernel_launch(void* const* d_in, const int* in_sizes, int n_in,
                              void* d_out, int out_size, void* d_ws, size_t ws_size,
                              hipStream_t stream)
{
    const float* u   = (const float*)d_in[0];
    const float* ab  = (const float*)d_in[1];
    const float* bb  = (const float*)d_in[2];
    const float* atc = (const float*)d_in[3];
    const float* btc = (const float*)d_in[4];
    float* out = (float*)d_out;
    float4* C4 = (float4*)d_ws;          // 33*512 float4 = 270336 B

    const int B = in_sizes[0] / (3 * 32 * 32);   // 2048
    const int blocksPerCh = B / 8;               // 256 (8 batches per 1-wave block)

    coef_kernel<<<17, 64, 0, stream>>>(ab, bb, atc, btc, C4);
    diff_kernel<<<3 * blocksPerCh, 64, 0, stream>>>(u, out, C4, blocksPerCh);
}